// Round 1
// baseline (244.331 us; speedup 1.0000x reference)
//
#include <hip/hip_runtime.h>
#include <stdint.h>

typedef unsigned short u16;
typedef __attribute__((ext_vector_type(8))) short s16x8;
typedef __attribute__((ext_vector_type(4))) float f32x4;

#define MFMA_BF16(a, b, c) __builtin_amdgcn_mfma_f32_16x16x32_bf16((a), (b), (c), 0, 0, 0)

static __device__ __forceinline__ u16 f2bf(float f) {
    uint32_t u = __float_as_uint(f);
    u = (u + 0x7fffu + ((u >> 16) & 1u)) >> 16;
    return (u16)u;
}

// ---------------- f32 -> bf16 linear convert (x) ----------------
__global__ void k_cvt_bf16(const float* __restrict__ in, u16* __restrict__ out) {
    int i = (blockIdx.x * 256 + threadIdx.x) * 8;
    f32x4 a = *(const f32x4*)(in + i);
    f32x4 b = *(const f32x4*)(in + i + 4);
    s16x8 r;
    r[0] = (short)f2bf(a[0]); r[1] = (short)f2bf(a[1]);
    r[2] = (short)f2bf(a[2]); r[3] = (short)f2bf(a[3]);
    r[4] = (short)f2bf(b[0]); r[5] = (short)f2bf(b[1]);
    r[6] = (short)f2bf(b[2]); r[7] = (short)f2bf(b[3]);
    *(s16x8*)(out + i) = r;
}

// ---------------- W [k][n] f32 -> Wt [n][k] bf16 (768x768, 4 weights) ----------------
__global__ void k_transpose_w(const float* __restrict__ w0, const float* __restrict__ w1,
                              const float* __restrict__ w2, const float* __restrict__ w3,
                              u16* __restrict__ t0, u16* __restrict__ t1,
                              u16* __restrict__ t2, u16* __restrict__ t3) {
    __shared__ float tile[32][33];
    const float* W; u16* T;
    switch (blockIdx.z) {
        case 0:  W = w0; T = t0; break;
        case 1:  W = w1; T = t1; break;
        case 2:  W = w2; T = t2; break;
        default: W = w3; T = t3; break;
    }
    int n0 = blockIdx.x * 32, k0 = blockIdx.y * 32;
    int tx = threadIdx.x, ty = threadIdx.y;
#pragma unroll
    for (int i = 0; i < 4; ++i)
        tile[ty + 8 * i][tx] = W[(size_t)(k0 + ty + 8 * i) * 768 + n0 + tx];
    __syncthreads();
#pragma unroll
    for (int i = 0; i < 4; ++i)
        T[(size_t)(n0 + ty + 8 * i) * 768 + k0 + tx] = f2bf(tile[tx][ty + 8 * i]);
}

// ---------------- bf16 GEMM: C[M=4096][N=768] = A[4096][768] * Bt[768][768]^T + bias ----
// MODE 0: scatter bf16 into [b*12+h][2048][64] (QKV).  MODE 1: f32 out[m][n] (out-proj).
template <int MODE>
__global__ __launch_bounds__(256) void k_gemm64(const u16* __restrict__ A,
                                                const u16* __restrict__ Bt,
                                                const float* __restrict__ bias,
                                                void* __restrict__ outp) {
    __shared__ u16 lA[64 * 64];
    __shared__ u16 lB[64 * 64];
    const int t = threadIdx.x;
    const int lane = t & 63, w = t >> 6;
    const int wr = w >> 1, wc = w & 1;
    const int c = lane & 15, g = lane >> 4;
    const int m0 = blockIdx.y * 64, n0 = blockIdx.x * 64;
    f32x4 acc[2][2] = {};
    const int r = t >> 2, p = t & 3;
    const int swz = (r & 7) << 3;                // XOR-swizzle, short units (16B granules)
    const int wo0 = r * 64 + ((p * 16) ^ swz);
    const int wo1 = r * 64 + ((p * 16 + 8) ^ swz);
    const u16* gA = A + (size_t)(m0 + r) * 768 + p * 16;
    const u16* gB = Bt + (size_t)(n0 + r) * 768 + p * 16;
    for (int kb = 0; kb < 768; kb += 64) {
        *(s16x8*)&lA[wo0] = *(const s16x8*)(gA + kb);
        *(s16x8*)&lA[wo1] = *(const s16x8*)(gA + kb + 8);
        *(s16x8*)&lB[wo0] = *(const s16x8*)(gB + kb);
        *(s16x8*)&lB[wo1] = *(const s16x8*)(gB + kb + 8);
        __syncthreads();
#pragma unroll
        for (int st = 0; st < 2; ++st) {
            s16x8 af[2], bf[2];
            const int col = st * 32 + g * 8;
#pragma unroll
            for (int i = 0; i < 2; ++i) {
                int ra = wr * 32 + i * 16 + c;
                af[i] = *(const s16x8*)&lA[ra * 64 + (col ^ ((ra & 7) << 3))];
                int rb = wc * 32 + i * 16 + c;
                bf[i] = *(const s16x8*)&lB[rb * 64 + (col ^ ((rb & 7) << 3))];
            }
#pragma unroll
            for (int i = 0; i < 2; ++i)
#pragma unroll
                for (int j = 0; j < 2; ++j)
                    acc[i][j] = MFMA_BF16(af[i], bf[j], acc[i][j]);
        }
        __syncthreads();
    }
#pragma unroll
    for (int i = 0; i < 2; ++i) {
#pragma unroll
        for (int j = 0; j < 2; ++j) {
            const int n = n0 + wc * 32 + j * 16 + c;
            const float bv = bias[n];
#pragma unroll
            for (int rr = 0; rr < 4; ++rr) {
                const int m = m0 + wr * 32 + i * 16 + g * 4 + rr;
                const float v = acc[i][j][rr] + bv;
                if (MODE == 0) {
                    const int b = m >> 11, s = m & 2047, h = n >> 6, hd = n & 63;
                    ((u16*)outp)[(((size_t)(b * 12 + h) * 2048 + s) << 6) + hd] = f2bf(v);
                } else {
                    ((float*)outp)[(size_t)m * 768 + n] = v;
                }
            }
        }
    }
}

// ---------------- causal flash attention ----------------
// grid: (B*H) * (S/64) blocks; 256 thr = 4 waves, wave w owns q rows qb*64+w*16 .. +15
__global__ __launch_bounds__(256) void k_attn(const u16* __restrict__ qw,
                                              const u16* __restrict__ kw,
                                              const u16* __restrict__ vw,
                                              u16* __restrict__ ctxb) {
    __shared__ u16 lK[64 * 64];     // K chunk [key][hd], XOR-swizzled rows (128B)
    __shared__ u16 lV[64 * 72];     // V^T chunk [hd][key], stride 72 (pad, conflict-free b128)
    __shared__ u16 lP[4][16 * 32];  // per-wave P [q][key32], row-major
    const int bh = blockIdx.x >> 5, qb = blockIdx.x & 31;
    const int t = threadIdx.x, lane = t & 63, w = t >> 6;
    const int c = lane & 15, g = lane >> 4;
    const int q0w = qb * 64 + w * 16;
    const u16* qp = qw + (size_t)bh * 2048 * 64;
    const u16* kp = kw + (size_t)bh * 2048 * 64;
    const u16* vp = vw + (size_t)bh * 2048 * 64;
    s16x8 qf[2];
#pragma unroll
    for (int st = 0; st < 2; ++st)
        qf[st] = *(const s16x8*)&qp[(size_t)(q0w + c) * 64 + st * 32 + g * 8];
    f32x4 ctx[4] = {};              // ctx^T: [hd = s4*16+4g+rr][q=c]
    float m2 = -1e30f, ssum = 0.0f;
    const float C2 = 0.18033688011112042f;  // (1/8) * log2(e)
    const int r = t >> 2, p = t & 3;
    const int swz = (r & 7) << 3;
    u16* Pw = &lP[w][0];
    for (int ch = 0; ch <= qb; ++ch) {
        {   // stage K (swizzled) and V^T (transposed scatter)
            const u16* gk = kp + (size_t)(ch * 64 + r) * 64 + p * 16;
            *(s16x8*)&lK[r * 64 + ((p * 16) ^ swz)] = *(const s16x8*)gk;
            *(s16x8*)&lK[r * 64 + ((p * 16 + 8) ^ swz)] = *(const s16x8*)(gk + 8);
            const u16* gv = vp + (size_t)(ch * 64 + r) * 64 + p * 16;
            s16x8 v0 = *(const s16x8*)gv;
            s16x8 v1 = *(const s16x8*)(gv + 8);
#pragma unroll
            for (int j2 = 0; j2 < 8; ++j2) lV[(p * 16 + j2) * 72 + r] = (u16)v0[j2];
#pragma unroll
            for (int j2 = 0; j2 < 8; ++j2) lV[(p * 16 + 8 + j2) * 72 + r] = (u16)v1[j2];
        }
        __syncthreads();
#pragma unroll
        for (int h2 = 0; h2 < 2; ++h2) {
            const int K0 = ch * 64 + h2 * 32;
            if (K0 <= q0w) {        // wave-uniform causal skip
                f32x4 sa = {0.f, 0.f, 0.f, 0.f}, sb = {0.f, 0.f, 0.f, 0.f};
#pragma unroll
                for (int st = 0; st < 2; ++st) {
                    const int col = st * 32 + g * 8;
                    const int ra = h2 * 32 + c;
                    const int rb = h2 * 32 + 16 + c;
                    s16x8 kf0 = *(const s16x8*)&lK[ra * 64 + (col ^ ((ra & 7) << 3))];
                    s16x8 kf1 = *(const s16x8*)&lK[rb * 64 + (col ^ ((rb & 7) << 3))];
                    sa = MFMA_BF16(kf0, qf[st], sa);   // S^T[key][q]
                    sb = MFMA_BF16(kf1, qf[st], sb);
                }
                const int qg = q0w + c;
                float tv[8];
#pragma unroll
                for (int rr = 0; rr < 4; ++rr) {
                    const int keyA = K0 + 4 * g + rr;
                    tv[rr] = (keyA <= qg) ? sa[rr] * C2 : -1e30f;
                    const int keyB = K0 + 16 + 4 * g + rr;
                    tv[4 + rr] = (keyB <= qg) ? sb[rr] * C2 : -1e30f;
                }
                float mt = tv[0];
#pragma unroll
                for (int rr = 1; rr < 8; ++rr) mt = fmaxf(mt, tv[rr]);
                mt = fmaxf(mt, __shfl_xor(mt, 16));
                mt = fmaxf(mt, __shfl_xor(mt, 32));
                const float mnew = fmaxf(m2, mt);
                const float fac = exp2f(m2 - mnew);
                float pv[8], ps = 0.f;
#pragma unroll
                for (int rr = 0; rr < 8; ++rr) { pv[rr] = exp2f(tv[rr] - mnew); ps += pv[rr]; }
                ps += __shfl_xor(ps, 16);
                ps += __shfl_xor(ps, 32);
                ssum = ssum * fac + ps;
                m2 = mnew;
#pragma unroll
                for (int s4 = 0; s4 < 4; ++s4) ctx[s4] *= fac;
                // stash P (bf16) into per-wave LDS, reread in x32 B-frag layout
                uint32_t u01 = (uint32_t)f2bf(pv[0]) | ((uint32_t)f2bf(pv[1]) << 16);
                uint32_t u23 = (uint32_t)f2bf(pv[2]) | ((uint32_t)f2bf(pv[3]) << 16);
                uint32_t u45 = (uint32_t)f2bf(pv[4]) | ((uint32_t)f2bf(pv[5]) << 16);
                uint32_t u67 = (uint32_t)f2bf(pv[6]) | ((uint32_t)f2bf(pv[7]) << 16);
                *(uint32_t*)&Pw[c * 32 + 4 * g] = u01;
                *(uint32_t*)&Pw[c * 32 + 4 * g + 2] = u23;
                *(uint32_t*)&Pw[c * 32 + 16 + 4 * g] = u45;
                *(uint32_t*)&Pw[c * 32 + 16 + 4 * g + 2] = u67;
                asm volatile("s_waitcnt lgkmcnt(0)" ::: "memory");
                s16x8 pf = *(const s16x8*)&Pw[c * 32 + 8 * g];
#pragma unroll
                for (int s4 = 0; s4 < 4; ++s4) {
                    s16x8 vf = *(const s16x8*)&lV[(s4 * 16 + c) * 72 + h2 * 32 + 8 * g];
                    ctx[s4] = MFMA_BF16(vf, pf, ctx[s4]);  // ctx^T[hd][q]
                }
            }
        }
        __syncthreads();
    }
    const float inv = 1.0f / ssum;
    const int b = bh / 12, h = bh - b * 12;
    const int qs = q0w + c;
#pragma unroll
    for (int s4 = 0; s4 < 4; ++s4)
#pragma unroll
        for (int rr = 0; rr < 4; ++rr) {
            const int hd = s4 * 16 + 4 * g + rr;
            ctxb[(size_t)(b * 2048 + qs) * 768 + h * 64 + hd] = f2bf(ctx[s4][rr] * inv);
        }
}

// ---------------- launch ----------------
extern "C" void kernel_launch(void* const* d_in, const int* in_sizes, int n_in,
                              void* d_out, int out_size, void* d_ws, size_t ws_size,
                              hipStream_t stream) {
    (void)in_sizes; (void)n_in; (void)out_size; (void)ws_size;
    const float* x  = (const float*)d_in[0];
    const float* Wq = (const float*)d_in[1];
    const float* bq = (const float*)d_in[2];
    const float* Wk = (const float*)d_in[3];
    const float* bk = (const float*)d_in[4];
    const float* Wv = (const float*)d_in[5];
    const float* bv = (const float*)d_in[6];
    const float* Wo = (const float*)d_in[7];
    const float* bo = (const float*)d_in[8];
    char* ws = (char*)d_ws;
    u16* xb   = (u16*)(ws);               // 4096*768 bf16      = 6291456 B
    u16* wqt  = (u16*)(ws + 6291456);     // 768*768 bf16 (W^T) = 1179648 B
    u16* wkt  = (u16*)(ws + 7471104);
    u16* wvt  = (u16*)(ws + 8650752);
    u16* wot  = (u16*)(ws + 9830400);
    u16* qwv  = (u16*)(ws + 11010048);    // [24][2048][64] bf16 = 6291456 B
    u16* kwv  = (u16*)(ws + 17301504);
    u16* vwv  = (u16*)(ws + 23592960);
    u16* ctx  = (u16*)(ws + 29884416);    // [4096][768] bf16
    float* out = (float*)d_out;

    k_cvt_bf16<<<1536, 256, 0, stream>>>(x, xb);
    k_transpose_w<<<dim3(24, 24, 4), dim3(32, 8), 0, stream>>>(Wq, Wk, Wv, Wo, wqt, wkt, wvt, wot);
    k_gemm64<0><<<dim3(12, 64), 256, 0, stream>>>(xb, wqt, bq, qwv);
    k_gemm64<0><<<dim3(12, 64), 256, 0, stream>>>(xb, wkt, bk, kwv);
    k_gemm64<0><<<dim3(12, 64), 256, 0, stream>>>(xb, wvt, bv, vwv);
    k_attn<<<768, 256, 0, stream>>>(qwv, kwv, vwv, ctx);
    k_gemm64<1><<<dim3(12, 64), 256, 0, stream>>>(ctx, wot, bo, out);
}

// Round 3
// 217.968 us; speedup vs baseline: 1.1210x; 1.1210x over previous
//
#include <hip/hip_runtime.h>
#include <stdint.h>

typedef unsigned short u16;
typedef __attribute__((ext_vector_type(8))) short s16x8;
typedef __attribute__((ext_vector_type(4))) float f32x4;

#define MFMA_BF16(a, b, c) __builtin_amdgcn_mfma_f32_16x16x32_bf16((a), (b), (c), 0, 0, 0)

typedef const __attribute__((address_space(1))) uint32_t* gas1_t;
typedef __attribute__((address_space(3))) uint32_t* las3_t;
#define GLDS16(dst, src) __builtin_amdgcn_global_load_lds((gas1_t)(src), (las3_t)(dst), 16, 0, 0)

static __device__ __forceinline__ u16 f2bf(float f) {
    uint32_t u = __float_as_uint(f);
    u = (u + 0x7fffu + ((u >> 16) & 1u)) >> 16;
    return (u16)u;
}
static __device__ __forceinline__ uint32_t pk2bf(float a, float b) {
    return (uint32_t)f2bf(a) | ((uint32_t)f2bf(b) << 16);
}

// ---------------- f32 -> bf16 linear convert (x) ----------------
__global__ void k_cvt_bf16(const float* __restrict__ in, u16* __restrict__ out) {
    int i = (blockIdx.x * 256 + threadIdx.x) * 8;
    f32x4 a = *(const f32x4*)(in + i);
    f32x4 b = *(const f32x4*)(in + i + 4);
    s16x8 r;
    r[0] = (short)f2bf(a[0]); r[1] = (short)f2bf(a[1]);
    r[2] = (short)f2bf(a[2]); r[3] = (short)f2bf(a[3]);
    r[4] = (short)f2bf(b[0]); r[5] = (short)f2bf(b[1]);
    r[6] = (short)f2bf(b[2]); r[7] = (short)f2bf(b[3]);
    *(s16x8*)(out + i) = r;
}

// ---------------- W [k][n] f32 -> Wt [n][k] bf16 (768x768, 4 weights) ----------------
__global__ void k_transpose_w(const float* __restrict__ w0, const float* __restrict__ w1,
                              const float* __restrict__ w2, const float* __restrict__ w3,
                              u16* __restrict__ t0, u16* __restrict__ t1,
                              u16* __restrict__ t2, u16* __restrict__ t3) {
    __shared__ float tile[32][33];
    const float* W; u16* T;
    switch (blockIdx.z) {
        case 0:  W = w0; T = t0; break;
        case 1:  W = w1; T = t1; break;
        case 2:  W = w2; T = t2; break;
        default: W = w3; T = t3; break;
    }
    int n0 = blockIdx.x * 32, k0 = blockIdx.y * 32;
    int tx = threadIdx.x, ty = threadIdx.y;
#pragma unroll
    for (int i = 0; i < 4; ++i)
        tile[ty + 8 * i][tx] = W[(size_t)(k0 + ty + 8 * i) * 768 + n0 + tx];
    __syncthreads();
#pragma unroll
    for (int i = 0; i < 4; ++i)
        T[(size_t)(n0 + ty + 8 * i) * 768 + k0 + tx] = f2bf(tile[tx][ty + 8 * i]);
}

// ---------------- fused QKV GEMM: 64x64 tile, global_load_lds staging ----------------
// grid (36, 64): blockIdx.x/12 selects weight (0=Q,1=K,2=V); 768 K-dim.
// sel 0/1: scatter bf16 into [bh][2048][64]; sel 2: scatter V^T bf16 into [bh][64][2048].
__global__ __launch_bounds__(256) void k_gemm_qkv(
        const u16* __restrict__ A,
        const u16* __restrict__ btq, const u16* __restrict__ btk, const u16* __restrict__ btv,
        const float* __restrict__ bq, const float* __restrict__ bk, const float* __restrict__ bv,
        u16* __restrict__ outq, u16* __restrict__ outk, u16* __restrict__ outv) {
    __shared__ u16 lA[64 * 64];
    __shared__ u16 lB[64 * 64];
    const int bx = blockIdx.x, sel = bx / 12, nb = bx - sel * 12;
    const u16* Bt; const float* bias; u16* outp;
    if (sel == 0)      { Bt = btq; bias = bq; outp = outq; }
    else if (sel == 1) { Bt = btk; bias = bk; outp = outk; }
    else               { Bt = btv; bias = bv; outp = outv; }
    const int t = threadIdx.x;
    const int lane = t & 63, w = t >> 6;
    const int wr = w >> 1, wc = w & 1;
    const int c = lane & 15, g = lane >> 4;
    const int m0 = blockIdx.y * 64, n0 = nb * 64;
    f32x4 acc[2][2] = {};
    // staging: linear LDS dest (wave-uniform base), pre-swizzled global source.
    // LDS content at (row r, 16B-granule q) = global granule (q ^ (r&7)).
    const int lr = lane >> 3, lq = lane & 7;
    const int sq = (lq ^ lr) * 8;  // swizzled k-offset in u16
    const u16* gA0 = A  + (size_t)(m0 + w * 16 + lr) * 768 + sq;
    const u16* gA1 = gA0 + 8 * 768;
    const u16* gB0 = Bt + (size_t)(n0 + w * 16 + lr) * 768 + sq;
    const u16* gB1 = gB0 + 8 * 768;
    u16* dA0 = &lA[w * 1024];
    u16* dA1 = &lA[w * 1024 + 512];
    u16* dB0 = &lB[w * 1024];
    u16* dB1 = &lB[w * 1024 + 512];
    for (int kb = 0; kb < 768; kb += 64) {
        GLDS16(dA0, gA0 + kb); GLDS16(dA1, gA1 + kb);
        GLDS16(dB0, gB0 + kb); GLDS16(dB1, gB1 + kb);
        __syncthreads();   // drains vmcnt (global_load_lds) + lgkm
#pragma unroll
        for (int st = 0; st < 2; ++st) {
            s16x8 af[2], bf[2];
            const int col = st * 32 + g * 8;
#pragma unroll
            for (int i = 0; i < 2; ++i) {
                int ra = wr * 32 + i * 16 + c;
                af[i] = *(const s16x8*)&lA[ra * 64 + (col ^ ((ra & 7) << 3))];
                int rb = wc * 32 + i * 16 + c;
                bf[i] = *(const s16x8*)&lB[rb * 64 + (col ^ ((rb & 7) << 3))];
            }
#pragma unroll
            for (int i = 0; i < 2; ++i)
#pragma unroll
                for (int j = 0; j < 2; ++j)
                    acc[i][j] = MFMA_BF16(af[i], bf[j], acc[i][j]);
        }
        __syncthreads();
    }
    if (sel < 2) {  // Q/K: [bh][s][hd] bf16
#pragma unroll
        for (int i = 0; i < 2; ++i)
#pragma unroll
            for (int j = 0; j < 2; ++j) {
                const int n = n0 + wc * 32 + j * 16 + c;
                const int h = n >> 6, hd = n & 63;
                const float bvv = bias[n];
#pragma unroll
                for (int rr = 0; rr < 4; ++rr) {
                    const int m = m0 + wr * 32 + i * 16 + g * 4 + rr;
                    const int b = m >> 11, s = m & 2047;
                    outp[(((size_t)(b * 12 + h) * 2048 + s) << 6) + hd] = f2bf(acc[i][j][rr] + bvv);
                }
            }
    } else {        // V^T: [bh][hd][s] bf16, 4 consecutive s packed per store
#pragma unroll
        for (int i = 0; i < 2; ++i)
#pragma unroll
            for (int j = 0; j < 2; ++j) {
                const int n = n0 + wc * 32 + j * 16 + c;
                const int h = n >> 6, hd = n & 63;
                const float bvv = bias[n];
                const int m = m0 + wr * 32 + i * 16 + g * 4;
                const int b = m >> 11, s = m & 2047;
                uint32_t lo = pk2bf(acc[i][j][0] + bvv, acc[i][j][1] + bvv);
                uint32_t hi = pk2bf(acc[i][j][2] + bvv, acc[i][j][3] + bvv);
                uint64_t pk = ((uint64_t)hi << 32) | lo;
                *(uint64_t*)&outp[((size_t)(b * 12 + h) * 64 + hd) * 2048 + s] = pk;
            }
    }
}

// ---------------- out-projection GEMM: f32 out = ctx(bf16) @ Wo^T + bo ----------------
__global__ __launch_bounds__(256) void k_gemm_out(const u16* __restrict__ A,
                                                  const u16* __restrict__ Bt,
                                                  const float* __restrict__ bias,
                                                  float* __restrict__ out) {
    __shared__ u16 lA[64 * 64];
    __shared__ u16 lB[64 * 64];
    const int t = threadIdx.x;
    const int lane = t & 63, w = t >> 6;
    const int wr = w >> 1, wc = w & 1;
    const int c = lane & 15, g = lane >> 4;
    const int m0 = blockIdx.y * 64, n0 = blockIdx.x * 64;
    f32x4 acc[2][2] = {};
    const int lr = lane >> 3, lq = lane & 7;
    const int sq = (lq ^ lr) * 8;
    const u16* gA0 = A  + (size_t)(m0 + w * 16 + lr) * 768 + sq;
    const u16* gA1 = gA0 + 8 * 768;
    const u16* gB0 = Bt + (size_t)(n0 + w * 16 + lr) * 768 + sq;
    const u16* gB1 = gB0 + 8 * 768;
    u16* dA0 = &lA[w * 1024];
    u16* dA1 = &lA[w * 1024 + 512];
    u16* dB0 = &lB[w * 1024];
    u16* dB1 = &lB[w * 1024 + 512];
    for (int kb = 0; kb < 768; kb += 64) {
        GLDS16(dA0, gA0 + kb); GLDS16(dA1, gA1 + kb);
        GLDS16(dB0, gB0 + kb); GLDS16(dB1, gB1 + kb);
        __syncthreads();
#pragma unroll
        for (int st = 0; st < 2; ++st) {
            s16x8 af[2], bf[2];
            const int col = st * 32 + g * 8;
#pragma unroll
            for (int i = 0; i < 2; ++i) {
                int ra = wr * 32 + i * 16 + c;
                af[i] = *(const s16x8*)&lA[ra * 64 + (col ^ ((ra & 7) << 3))];
                int rb = wc * 32 + i * 16 + c;
                bf[i] = *(const s16x8*)&lB[rb * 64 + (col ^ ((rb & 7) << 3))];
            }
#pragma unroll
            for (int i = 0; i < 2; ++i)
#pragma unroll
                for (int j = 0; j < 2; ++j)
                    acc[i][j] = MFMA_BF16(af[i], bf[j], acc[i][j]);
        }
        __syncthreads();
    }
#pragma unroll
    for (int i = 0; i < 2; ++i)
#pragma unroll
        for (int j = 0; j < 2; ++j) {
            const int n = n0 + wc * 32 + j * 16 + c;
            const float bvv = bias[n];
#pragma unroll
            for (int rr = 0; rr < 4; ++rr) {
                const int m = m0 + wr * 32 + i * 16 + g * 4 + rr;
                out[(size_t)m * 768 + n] = acc[i][j][rr] + bvv;
            }
        }
}

// ---------------- causal flash attention: 1 wave / block, 16 q-rows ----------------
// grid = 24*128 = 3072 blocks of 64 threads, launched in descending-work order.
// K read direct from global ([bh][s][64], L2-resident); V read direct from V^T [bh][64][s].
__global__ __launch_bounds__(64) void k_attn(const u16* __restrict__ qw,
                                             const u16* __restrict__ kw,
                                             const u16* __restrict__ vt,
                                             u16* __restrict__ ctxb) {
    __shared__ u16 lP[16 * 68];   // per-wave P^T [q=16][key=64], row stride 68 (banking)
    const int bid = blockIdx.x;
    const int qt = 127 - bid / 24;     // big tiles dispatch first (load balance)
    const int bh = bid % 24;
    const int lane = threadIdx.x & 63;
    const int c = lane & 15, g = lane >> 4;
    const int q0 = qt * 16;
    const u16* qp = qw + (size_t)bh * 2048 * 64;
    const u16* kp = kw + (size_t)bh * 2048 * 64;
    const u16* vp = vt + (size_t)bh * 64 * 2048;
    const s16x8 qf0 = *(const s16x8*)&qp[(size_t)(q0 + c) * 64 + g * 8];
    const s16x8 qf1 = *(const s16x8*)&qp[(size_t)(q0 + c) * 64 + 32 + g * 8];
    f32x4 ctx[4] = {};                 // ctx^T: [hd = s4*16+4g+rr][q = c]
    float m2 = -1e30f, ssum = 0.0f;
    const float C2 = 0.18033688011112042f;  // (1/8) * log2(e)
    const int nk = q0 + 16;
    for (int Kc = 0; Kc < nk; Kc += 64) {
        // ---- QK^T for 64 keys: S^T[key][q] ----
        f32x4 sv[4];
#pragma unroll
        for (int u = 0; u < 4; ++u) {
            const u16* krow = kp + (size_t)(Kc + u * 16 + c) * 64;
            s16x8 k0 = *(const s16x8*)(krow + g * 8);
            s16x8 k1 = *(const s16x8*)(krow + 32 + g * 8);
            f32x4 a = {0.f, 0.f, 0.f, 0.f};
            a = MFMA_BF16(k0, qf0, a);
            a = MFMA_BF16(k1, qf1, a);
            sv[u] = a;
        }
        // ---- prefetch V frags (latency hides under softmax) ----
        s16x8 vfr[2][4];
#pragma unroll
        for (int h2 = 0; h2 < 2; ++h2)
#pragma unroll
            for (int s4 = 0; s4 < 4; ++s4)
                vfr[h2][s4] = *(const s16x8*)&vp[(size_t)(s4 * 16 + c) * 2048 + Kc + h2 * 32 + g * 8];
        // ---- online softmax over 64 keys ----
        float tv[16];
        if (Kc + 63 <= q0) {           // fully-unmasked chunk (wave-uniform)
#pragma unroll
            for (int i = 0; i < 16; ++i) tv[i] = sv[i >> 2][i & 3] * C2;
        } else {
            const int qg = q0 + c;
#pragma unroll
            for (int u = 0; u < 4; ++u)
#pragma unroll
                for (int rr = 0; rr < 4; ++rr) {
                    const int key = Kc + u * 16 + 4 * g + rr;
                    tv[u * 4 + rr] = (key <= qg) ? sv[u][rr] * C2 : -1e30f;
                }
        }
        float mt = tv[0];
#pragma unroll
        for (int i = 1; i < 16; ++i) mt = fmaxf(mt, tv[i]);
        mt = fmaxf(mt, __shfl_xor(mt, 16));
        mt = fmaxf(mt, __shfl_xor(mt, 32));
        const float mnew = fmaxf(m2, mt);
        const float fac = exp2f(m2 - mnew);
        float p[16], ps = 0.f;
#pragma unroll
        for (int i = 0; i < 16; ++i) { p[i] = exp2f(tv[i] - mnew); ps += p[i]; }
        ps += __shfl_xor(ps, 16);
        ps += __shfl_xor(ps, 32);
        ssum = ssum * fac + ps;
        m2 = mnew;
#pragma unroll
        for (int s4 = 0; s4 < 4; ++s4) ctx[s4] *= fac;
        // ---- P^T -> LDS (b64 writes), reread as PV B-frags (b128, conflict-free) ----
#pragma unroll
        for (int u = 0; u < 4; ++u) {
            uint64_t pk = (uint64_t)pk2bf(p[u * 4], p[u * 4 + 1]) |
                          ((uint64_t)pk2bf(p[u * 4 + 2], p[u * 4 + 3]) << 32);
            *(uint64_t*)&lP[c * 68 + u * 16 + 4 * g] = pk;
        }
        asm volatile("s_waitcnt lgkmcnt(0)" ::: "memory");
#pragma unroll
        for (int h2 = 0; h2 < 2; ++h2) {
            s16x8 pf = *(const s16x8*)&lP[c * 68 + h2 * 32 + 8 * g];
#pragma unroll
            for (int s4 = 0; s4 < 4; ++s4)
                ctx[s4] = MFMA_BF16(vfr[h2][s4], pf, ctx[s4]);   // ctx^T += V^T · P^T
        }
        asm volatile("" ::: "memory");   // keep next iter's lP writes below these reads
    }
    const float inv = 1.0f / ssum;
    const int b = bh / 12, h = bh - b * 12;
    const size_t rowbase = (size_t)(b * 2048 + q0 + c) * 768 + h * 64;
#pragma unroll
    for (int s4 = 0; s4 < 4; ++s4) {
        uint64_t pk = (uint64_t)pk2bf(ctx[s4][0] * inv, ctx[s4][1] * inv) |
                      ((uint64_t)pk2bf(ctx[s4][2] * inv, ctx[s4][3] * inv) << 32);
        *(uint64_t*)&ctxb[rowbase + s4 * 16 + 4 * g] = pk;
    }
}

// ---------------- launch ----------------
extern "C" void kernel_launch(void* const* d_in, const int* in_sizes, int n_in,
                              void* d_out, int out_size, void* d_ws, size_t ws_size,
                              hipStream_t stream) {
    (void)in_sizes; (void)n_in; (void)out_size; (void)ws_size;
    const float* x  = (const float*)d_in[0];
    const float* Wq = (const float*)d_in[1];
    const float* bq = (const float*)d_in[2];
    const float* Wk = (const float*)d_in[3];
    const float* bk = (const float*)d_in[4];
    const float* Wv = (const float*)d_in[5];
    const float* bv = (const float*)d_in[6];
    const float* Wo = (const float*)d_in[7];
    const float* bo = (const float*)d_in[8];
    char* ws = (char*)d_ws;
    u16* xb   = (u16*)(ws);               // 4096*768 bf16      = 6291456 B
    u16* wqt  = (u16*)(ws + 6291456);     // 768*768 bf16 (W^T) = 1179648 B
    u16* wkt  = (u16*)(ws + 7471104);
    u16* wvt  = (u16*)(ws + 8650752);
    u16* wot  = (u16*)(ws + 9830400);
    u16* qwv  = (u16*)(ws + 11010048);    // [24][2048][64] bf16 = 6291456 B
    u16* kwv  = (u16*)(ws + 17301504);
    u16* vtw  = (u16*)(ws + 23592960);    // V^T [24][64][2048] bf16
    u16* ctx  = (u16*)(ws + 29884416);    // [4096][768] bf16
    float* out = (float*)d_out;

    k_cvt_bf16<<<1536, 256, 0, stream>>>(x, xb);
    k_transpose_w<<<dim3(24, 24, 4), dim3(32, 8), 0, stream>>>(Wq, Wk, Wv, Wo, wqt, wkt, wvt, wot);
    k_gemm_qkv<<<dim3(36, 64), 256, 0, stream>>>(xb, wqt, wkt, wvt, bq, bk, bv, qwv, kwv, vtw);
    k_attn<<<3072, 64, 0, stream>>>(qwv, kwv, vtw, ctx);
    k_gemm_out<<<dim3(12, 64), 256, 0, stream>>>(ctx, wot, bo, out);
}